// Round 4
// baseline (776.499 us; speedup 1.0000x reference)
//
#include <hip/hip_runtime.h>
#include <hip/hip_bf16.h>
#include <stdint.h>

#define HID     128
#define OUTC    10
#define NGRAPH  512
#define NPART   8

using bf16x8 = __attribute__((ext_vector_type(8))) short;
using f32x4  = __attribute__((ext_vector_type(4))) float;

__device__ __forceinline__ short f2bf(float f) {
    __hip_bfloat16 h = __float2bfloat16(f);
    return *reinterpret_cast<short*>(&h);
}
__device__ __forceinline__ float bf2f(short s) {
    union { uint32_t u; float f; } x; x.u = ((uint32_t)(uint16_t)s) << 16; return x.f;
}
__device__ __forceinline__ float bflo(uint32_t v) {
    union { uint32_t u; float f; } x; x.u = v << 16; return x.f;
}
__device__ __forceinline__ float bfhi(uint32_t v) {
    union { uint32_t u; float f; } x; x.u = v & 0xffff0000u; return x.f;
}

// ---------------------------------------------------------------------------
// int64-vs-int32 layout detection (wave-parallel)
// ---------------------------------------------------------------------------
__global__ void detect64_kernel(const int* __restrict__ ei, int* __restrict__ flag) {
    int lane = threadIdx.x & 63;
    int v = ei[2 * lane + 1];
    unsigned long long b = __ballot(v == 0);
    if (threadIdx.x == 0) *flag = (b == ~0ULL) ? 1 : 0;
}

__device__ __forceinline__ int fetch_idx(const int* __restrict__ p, long j, int f64) {
    return p[f64 ? (j << 1) : j];
}

// ---------------------------------------------------------------------------
// CSR build phase 1: in-degree histogram, XCD-partitioned by dst range.
// part = blockIdx & 7 -> (round-robin) one XCD owns each deg line.
// ---------------------------------------------------------------------------
__global__ void __launch_bounds__(256) deg_kernel(
        const int* __restrict__ ei, const int* __restrict__ flag,
        int* __restrict__ deg, long E, int psize) {
    const int part   = blockIdx.x & (NPART - 1);
    const int chunk  = blockIdx.x >> 3;
    const int nchunk = gridDim.x >> 3;
    const int f  = *flag;
    const int lo = part * psize;
    const int hi = lo + psize;
    for (long e = (long)chunk * blockDim.x + threadIdx.x; e < E;
         e += (long)nchunk * blockDim.x) {
        int d = fetch_idx(ei, E + e, f);
        if (d >= lo && d < hi) atomicAdd(&deg[d], 1);
    }
}

__global__ void __launch_bounds__(1024) scan_kernel(const int* __restrict__ deg,
                                                    int* __restrict__ ofs, int n) {
    __shared__ int wsum[16];
    __shared__ int carry_s;
    __shared__ int chunk_tot;
    const int tid  = threadIdx.x;
    const int lane = tid & 63;
    const int wid  = tid >> 6;
    if (tid == 0) carry_s = 0;
    __syncthreads();
    const int CHUNK = 4096;  // 1024 threads x 4
    for (int base = 0; base < n; base += CHUNK) {
        int idx = base + tid * 4;
        int v[4];
#pragma unroll
        for (int j = 0; j < 4; ++j) v[j] = (idx + j < n) ? deg[idx + j] : 0;
        int s1 = v[0] + v[1] + v[2] + v[3];
        int inc = s1;
#pragma unroll
        for (int d = 1; d < 64; d <<= 1) {
            int t = __shfl_up(inc, d, 64);
            if (lane >= d) inc += t;
        }
        if (lane == 63) wsum[wid] = inc;
        __syncthreads();
        if (wid == 0) {
            int ws = (lane < 16) ? wsum[lane] : 0;
            int winc = ws;
#pragma unroll
            for (int d = 1; d < 16; d <<= 1) {
                int t = __shfl_up(winc, d, 64);
                if (lane >= d) winc += t;
            }
            if (lane == 15) chunk_tot = winc;
            if (lane < 16) wsum[lane] = winc - ws;
        }
        __syncthreads();
        int excl = carry_s + wsum[wid] + (inc - s1);
        int run = excl;
#pragma unroll
        for (int j = 0; j < 4; ++j) {
            if (idx + j < n) ofs[idx + j] = run;
            run += v[j];
        }
        __syncthreads();
        if (tid == 0) carry_s += chunk_tot;
        __syncthreads();
    }
    if (tid == 0) ofs[n] = carry_s;
}

__global__ void dinv_kernel(const int* __restrict__ deg, float* __restrict__ dinv, int n) {
    int i = blockIdx.x * blockDim.x + threadIdx.x;
    if (i < n) dinv[i] = rsqrtf((float)deg[i] + 1.0f);
}

// ---------------------------------------------------------------------------
// CSR build phase 2a: bucket-append scatter, XCD-partitioned by dst range.
// Each partition-group only writes pairs/bcnt lines in its own dst range ->
// no cross-XCD line ping-pong (writer locality, not just address locality).
// pairs[pos] = src | (dst&31)<<27
// ---------------------------------------------------------------------------
__global__ void __launch_bounds__(256) scatter_kernel(
        const int* __restrict__ ei, const int* __restrict__ flag,
        const int* __restrict__ ofs, int* __restrict__ bcnt,
        uint32_t* __restrict__ pairs, long E, int psize) {
    const int part   = blockIdx.x & (NPART - 1);
    const int chunk  = blockIdx.x >> 3;
    const int nchunk = gridDim.x >> 3;
    const int f  = *flag;
    const int lo = part * psize;
    const int hi = lo + psize;
    for (long e = (long)chunk * blockDim.x + threadIdx.x; e < E;
         e += (long)nchunk * blockDim.x) {
        int d = fetch_idx(ei, E + e, f);
        if (d >= lo && d < hi) {
            int s = fetch_idx(ei, e, f);
            int b = d >> 5;
            int pos = ofs[d & ~31] + atomicAdd(&bcnt[b], 1);
            pairs[pos] = (uint32_t)s | ((uint32_t)(d & 31) << 27);
        }
    }
}

// ---------------------------------------------------------------------------
// CSR build phase 2b: within each bucket, regroup pairs into per-node CSR
// order. deg gives local counts; contiguous reads/writes.
// ---------------------------------------------------------------------------
__global__ void __launch_bounds__(256) bucketize_kernel(
        const uint32_t* __restrict__ pairs, const int* __restrict__ deg,
        const int* __restrict__ ofs, int* __restrict__ col, int n) {
    __shared__ int lofs[32];
    __shared__ int lrank[32];
    const int b  = blockIdx.x;
    const int v0 = b * 32;
    const int nn = min(32, n - v0);
    const int tid = threadIdx.x;
    if (tid < 32) {
        int d = (tid < nn) ? deg[v0 + tid] : 0;
        int inc = d;
#pragma unroll
        for (int s = 1; s < 32; s <<= 1) {
            int t = __shfl_up(inc, s, 64);
            if (tid >= s) inc += t;
        }
        lofs[tid]  = inc - d;
        lrank[tid] = 0;
    }
    __syncthreads();
    const int base = ofs[v0];
    const int end  = ofs[v0 + nn];
    for (int i = base + tid; i < end; i += 256) {
        uint32_t v = pairs[i];
        int dl = (int)(v >> 27);
        int r  = atomicAdd(&lrank[dl], 1);
        col[base + lofs[dl] + r] = (int)(v & 0x07FFFFFFu);
    }
}

// ---------------------------------------------------------------------------
// Weight prep: Wt[w] = transpose(W_w) split into bf16 hi + lo planes.
// ---------------------------------------------------------------------------
__global__ void __launch_bounds__(128) wprep_kernel(
        const float* __restrict__ W0, const float* __restrict__ W1,
        const float* __restrict__ W2, short* __restrict__ Wt) {
    const float* W = (blockIdx.x == 0) ? W0 : (blockIdx.x == 1) ? W1 : W2;
    short* hi = Wt + (size_t)blockIdx.x * 2 * HID * HID;
    short* lo = hi + HID * HID;
    __shared__ float Ws[64][129];
    const int t = threadIdx.x;
    for (int half = 0; half < 2; ++half) {
        const int kbase = half * 64;
#pragma unroll
        for (int it = 0; it < 16; ++it) {
            int idx = (t + it * 128) * 4;
            int k = idx >> 7, c = idx & 127;
            float4 v = *(const float4*)(W + (size_t)(kbase + k) * HID + c);
            Ws[k][c] = v.x; Ws[k][c + 1] = v.y; Ws[k][c + 2] = v.z; Ws[k][c + 3] = v.w;
        }
        __syncthreads();
        for (int it = 0; it < 64; ++it) {
            int k2 = t & 63;
            int c  = (t >> 6) + it * 2;
            float w = Ws[k2][c];
            short h = f2bf(w);
            hi[(size_t)c * HID + kbase + k2] = h;
            lo[(size_t)c * HID + kbase + k2] = f2bf(w - bf2f(h));
        }
        __syncthreads();
    }
}

// ---------------------------------------------------------------------------
// hs = bf16( (A @ W) * dinv[:,None] ) — MFMA bf16, LDS-free, split-W hi+lo.
// ---------------------------------------------------------------------------
template<bool AFP32>
__global__ void __launch_bounds__(256) gemm_hs_kernel(
        const void* __restrict__ Ap, const short* __restrict__ Wt,
        const float* __restrict__ dinv, short* __restrict__ hs, int n) {
    const short* __restrict__ Bh = Wt;
    const short* __restrict__ Bl = Wt + HID * HID;
    const int tid = threadIdx.x;
    const int w  = tid >> 6;
    const int l  = tid & 63;
    const int lr = l & 15;
    const int kq = l >> 4;
    const int r0 = blockIdx.x * 128;

    f32x4 acc[8][2] = {};
    const int col0 = w * 32 + lr;
    const int col1 = w * 32 + 16 + lr;

    const float* Af = (const float*)Ap;
    const short* Ab = (const short*)Ap;

#pragma unroll
    for (int ks = 0; ks < 4; ++ks) {
        const int k0 = ks * 32 + kq * 8;
        bf16x8 a[8];
#pragma unroll
        for (int rf = 0; rf < 8; ++rf) {
            int row = r0 + rf * 16 + lr;
            if (row >= n) row = n - 1;
            if (AFP32) {
                const float* ap = Af + (size_t)row * HID + k0;
                float4 f0 = *(const float4*)ap;
                float4 f1 = *(const float4*)(ap + 4);
                bf16x8 tv;
                tv[0] = f2bf(f0.x); tv[1] = f2bf(f0.y); tv[2] = f2bf(f0.z); tv[3] = f2bf(f0.w);
                tv[4] = f2bf(f1.x); tv[5] = f2bf(f1.y); tv[6] = f2bf(f1.z); tv[7] = f2bf(f1.w);
                a[rf] = tv;
            } else {
                a[rf] = *(const bf16x8*)(Ab + (size_t)row * HID + k0);
            }
        }
        bf16x8 bh0 = *(const bf16x8*)(Bh + (size_t)col0 * HID + k0);
        bf16x8 bh1 = *(const bf16x8*)(Bh + (size_t)col1 * HID + k0);
        bf16x8 bl0 = *(const bf16x8*)(Bl + (size_t)col0 * HID + k0);
        bf16x8 bl1 = *(const bf16x8*)(Bl + (size_t)col1 * HID + k0);
#pragma unroll
        for (int rf = 0; rf < 8; ++rf) {
            acc[rf][0] = __builtin_amdgcn_mfma_f32_16x16x32_bf16(a[rf], bh0, acc[rf][0], 0, 0, 0);
            acc[rf][1] = __builtin_amdgcn_mfma_f32_16x16x32_bf16(a[rf], bh1, acc[rf][1], 0, 0, 0);
            acc[rf][0] = __builtin_amdgcn_mfma_f32_16x16x32_bf16(a[rf], bl0, acc[rf][0], 0, 0, 0);
            acc[rf][1] = __builtin_amdgcn_mfma_f32_16x16x32_bf16(a[rf], bl1, acc[rf][1], 0, 0, 0);
        }
    }
#pragma unroll
    for (int rf = 0; rf < 8; ++rf) {
#pragma unroll
        for (int rg = 0; rg < 4; ++rg) {
            int row = r0 + rf * 16 + kq * 4 + rg;
            if (row < n) {
                float dn = dinv[row];
                hs[(size_t)row * HID + col0] = f2bf(acc[rf][0][rg] * dn);
                hs[(size_t)row * HID + col1] = f2bf(acc[rf][1][rg] * dn);
            }
        }
    }
}

// ---------------------------------------------------------------------------
// out[d] = maybe_relu( dinv[d] * (hs[d] + sum_{e->d} hs[src]) + bias )  (bf16)
// one wave per node, lane = 2 channels, 8 outstanding gathers
// ---------------------------------------------------------------------------
__global__ void __launch_bounds__(256) agg_kernel(
        const short* __restrict__ hs, const float* __restrict__ dinv,
        const int* __restrict__ ofs, const int* __restrict__ col,
        const float* __restrict__ bias, short* __restrict__ out,
        int n, int do_relu) {
    int node = blockIdx.x * 4 + (threadIdx.x >> 6);
    if (node >= n) return;
    int lane = threadIdx.x & 63;
    const uint32_t* __restrict__ h2 = (const uint32_t*)hs;

    uint32_t sv = h2[(size_t)node * 64 + lane];
    float ax = bflo(sv), ay = bfhi(sv);
    int e0 = ofs[node], e1 = ofs[node + 1];
    int e = e0;
    for (; e + 8 <= e1; e += 8) {
        int s0 = col[e],     s1 = col[e + 1], s2 = col[e + 2], s3 = col[e + 3];
        int s4 = col[e + 4], s5 = col[e + 5], s6 = col[e + 6], s7 = col[e + 7];
        uint32_t v0 = h2[(size_t)s0 * 64 + lane];
        uint32_t v1 = h2[(size_t)s1 * 64 + lane];
        uint32_t v2 = h2[(size_t)s2 * 64 + lane];
        uint32_t v3 = h2[(size_t)s3 * 64 + lane];
        uint32_t v4 = h2[(size_t)s4 * 64 + lane];
        uint32_t v5 = h2[(size_t)s5 * 64 + lane];
        uint32_t v6 = h2[(size_t)s6 * 64 + lane];
        uint32_t v7 = h2[(size_t)s7 * 64 + lane];
        ax += bflo(v0) + bflo(v1) + bflo(v2) + bflo(v3)
            + bflo(v4) + bflo(v5) + bflo(v6) + bflo(v7);
        ay += bfhi(v0) + bfhi(v1) + bfhi(v2) + bfhi(v3)
            + bfhi(v4) + bfhi(v5) + bfhi(v6) + bfhi(v7);
    }
    for (; e < e1; ++e) {
        uint32_t v = h2[(size_t)col[e] * 64 + lane];
        ax += bflo(v); ay += bfhi(v);
    }
    float dn = dinv[node];
    float2 b = ((const float2*)bias)[lane];
    float ox = fmaf(ax, dn, b.x);
    float oy = fmaf(ay, dn, b.y);
    if (do_relu) { ox = fmaxf(ox, 0.f); oy = fmaxf(oy, 0.f); }
    uint32_t pk = (uint32_t)(uint16_t)f2bf(ox) | ((uint32_t)(uint16_t)f2bf(oy) << 16);
    ((uint32_t*)out)[(size_t)node * 64 + lane] = pk;
}

// ---------------------------------------------------------------------------
// pooling + MLP head
// ---------------------------------------------------------------------------
__global__ void boundary_kernel(const int* __restrict__ batch, const int* __restrict__ flag,
                                int* __restrict__ gstart, int n) {
    int i = blockIdx.x * blockDim.x + threadIdx.x;
    if (i >= n) return;
    int f = *flag;
    int b  = fetch_idx(batch, i, f);
    int bp = (i == 0) ? -1 : fetch_idx(batch, i - 1, f);
    for (int g = bp + 1; g <= b; ++g) gstart[g] = i;
    if (i == n - 1) {
        for (int g = b + 1; g <= NGRAPH; ++g) gstart[g] = n;
    }
}

__global__ void __launch_bounds__(128) pool_kernel(const short* __restrict__ h,
                                                   const int* __restrict__ gstart,
                                                   float* __restrict__ pooled) {
    int g = blockIdx.x, c = threadIdx.x;
    int s = gstart[g], e = gstart[g + 1];
    float acc = 0.f;
    int i = s;
    for (; i + 4 <= e; i += 4) {
        acc += bf2f(h[(size_t)i * HID + c]) + bf2f(h[(size_t)(i + 1) * HID + c])
             + bf2f(h[(size_t)(i + 2) * HID + c]) + bf2f(h[(size_t)(i + 3) * HID + c]);
    }
    for (; i < e; ++i) acc += bf2f(h[(size_t)i * HID + c]);
    float cnt = (float)(e - s);
    pooled[g * HID + c] = acc / fmaxf(cnt, 1.f);
}

__global__ void __launch_bounds__(128) mlp_kernel(
        const float* __restrict__ pooled,
        const float* __restrict__ W1, const float* __restrict__ b1,
        const float* __restrict__ W2, const float* __restrict__ b2,
        float* __restrict__ out) {
    __shared__ float p[HID];
    __shared__ float hid[HID];
    int g = blockIdx.x, c = threadIdx.x;
    p[c] = pooled[g * HID + c];
    __syncthreads();
    float a = b1[c];
#pragma unroll 8
    for (int k = 0; k < HID; ++k) a = fmaf(p[k], W1[k * HID + c], a);
    hid[c] = fmaxf(a, 0.f);
    __syncthreads();
    if (c < OUTC) {
        float o = b2[c];
#pragma unroll 8
        for (int k = 0; k < HID; ++k) o = fmaf(hid[k], W2[k * OUTC + c], o);
        out[g * OUTC + c] = o;
    }
}

// ---------------------------------------------------------------------------
extern "C" void kernel_launch(void* const* d_in, const int* in_sizes, int n_in,
                              void* d_out, int out_size, void* d_ws, size_t ws_size,
                              hipStream_t stream) {
    const float* x   = (const float*)d_in[0];
    const int*   ei  = (const int*)d_in[1];
    const int*   bat = (const int*)d_in[2];
    const float* Wc0 = (const float*)d_in[3];
    const float* bc0 = (const float*)d_in[4];
    const float* Wc1 = (const float*)d_in[5];
    const float* bc1 = (const float*)d_in[6];
    const float* Wc2 = (const float*)d_in[7];
    const float* bc2 = (const float*)d_in[8];
    const float* W1  = (const float*)d_in[9];
    const float* b1  = (const float*)d_in[10];
    const float* W2  = (const float*)d_in[11];
    const float* b2  = (const float*)d_in[12];
    float* out = (float*)d_out;

    const int  n = in_sizes[0] / HID;
    const long E = in_sizes[1] / 2;
    const int  NBUC  = (n + 31) / 32;
    const int  psize = (n + NPART - 1) / NPART;

    char* w = (char*)d_ws;
    size_t off = 0;
    auto carve = [&](size_t bytes) {
        void* p = w + off;
        off += (bytes + 255) & ~(size_t)255;
        return p;
    };
    int*   flag   = (int*)carve(4);
    int*   deg    = (int*)carve((size_t)n * 4);
    int*   ofs    = (int*)carve((size_t)(n + 1) * 4);
    int*   bcnt   = (int*)carve((size_t)NBUC * 4);
    float* dinv   = (float*)carve((size_t)n * 4);
    int*   gstart = (int*)carve((NGRAPH + 1) * 4);
    int*   col    = (int*)carve((size_t)E * 4);
    short* Wt     = (short*)carve((size_t)3 * 2 * HID * HID * 2);
    short* hs     = (short*)carve((size_t)n * HID * 2);
    short* h      = (short*)carve((size_t)n * HID * 2);
    float* pooled = (float*)carve((size_t)NGRAPH * HID * 4);
    uint32_t* pairs = (uint32_t*)h;   // alias: consumed before h is first written

    hipMemsetAsync(deg, 0, (size_t)n * 4, stream);
    hipMemsetAsync(bcnt, 0, (size_t)NBUC * 4, stream);

    detect64_kernel<<<1, 64, 0, stream>>>(ei, flag);

    const int pb = NPART * 128;   // 8 partition-groups x 128 chunks
    deg_kernel<<<pb, 256, 0, stream>>>(ei, flag, deg, E, psize);
    scan_kernel<<<1, 1024, 0, stream>>>(deg, ofs, n);
    dinv_kernel<<<(n + 255) / 256, 256, 0, stream>>>(deg, dinv, n);
    scatter_kernel<<<pb, 256, 0, stream>>>(ei, flag, ofs, bcnt, pairs, E, psize);
    bucketize_kernel<<<NBUC, 256, 0, stream>>>(pairs, deg, ofs, col, n);
    wprep_kernel<<<3, 128, 0, stream>>>(Wc0, Wc1, Wc2, Wt);

    const int gb = (n + 127) / 128;
    const int ab = (n + 3) / 4;
    const size_t WSTRIDE = (size_t)2 * HID * HID;
    // layer 0
    gemm_hs_kernel<true><<<gb, 256, 0, stream>>>(x, Wt, dinv, hs, n);
    agg_kernel<<<ab, 256, 0, stream>>>(hs, dinv, ofs, col, bc0, h, n, 1);
    // layer 1
    gemm_hs_kernel<false><<<gb, 256, 0, stream>>>(h, Wt + WSTRIDE, dinv, hs, n);
    agg_kernel<<<ab, 256, 0, stream>>>(hs, dinv, ofs, col, bc1, h, n, 1);
    // layer 2 (no relu)
    gemm_hs_kernel<false><<<gb, 256, 0, stream>>>(h, Wt + 2 * WSTRIDE, dinv, hs, n);
    agg_kernel<<<ab, 256, 0, stream>>>(hs, dinv, ofs, col, bc2, h, n, 0);

    boundary_kernel<<<(n + 255) / 256, 256, 0, stream>>>(bat, flag, gstart, n);
    pool_kernel<<<NGRAPH, 128, 0, stream>>>(h, gstart, pooled);
    mlp_kernel<<<NGRAPH, 128, 0, stream>>>(pooled, W1, b1, W2, b2, out);
}

// Round 5
// 543.712 us; speedup vs baseline: 1.4281x; 1.4281x over previous
//
#include <hip/hip_runtime.h>
#include <hip/hip_bf16.h>
#include <stdint.h>

#define HID     128
#define OUTC    10
#define NGRAPH  512
#define NPART   8          // writer partitions ~ XCDs
#define PSIZE   256        // nodes per bin
#define CAPPP   1024       // entries per (part,bin) sub-region (mean 511, 22 sd headroom)

using bf16x8 = __attribute__((ext_vector_type(8))) short;
using f32x4  = __attribute__((ext_vector_type(4))) float;

__device__ __forceinline__ short f2bf(float f) {
    __hip_bfloat16 h = __float2bfloat16(f);
    return *reinterpret_cast<short*>(&h);
}
__device__ __forceinline__ float bf2f(short s) {
    union { uint32_t u; float f; } x; x.u = ((uint32_t)(uint16_t)s) << 16; return x.f;
}
__device__ __forceinline__ float bflo(uint32_t v) {
    union { uint32_t u; float f; } x; x.u = v << 16; return x.f;
}
__device__ __forceinline__ float bfhi(uint32_t v) {
    union { uint32_t u; float f; } x; x.u = v & 0xffff0000u; return x.f;
}

// ---------------------------------------------------------------------------
// int64-vs-int32 layout detection (wave-parallel)
// ---------------------------------------------------------------------------
__global__ void detect64_kernel(const int* __restrict__ ei, int* __restrict__ flag) {
    int lane = threadIdx.x & 63;
    int v = ei[2 * lane + 1];
    unsigned long long b = __ballot(v == 0);
    if (threadIdx.x == 0) *flag = (b == ~0ULL) ? 1 : 0;
}

__device__ __forceinline__ int fetch_idx(const int* __restrict__ p, long j, int f64) {
    return p[f64 ? (j << 1) : j];
}

// ---------------------------------------------------------------------------
// CSR pass A: writer-partitioned bin scatter. Edge stream read ONCE.
// Block's part = blockIdx&7 (~XCD). Sub-region (part,bin) is appended only by
// one XCD's blocks -> tail lines stay in that XCD's L2, fill, write back once.
// entry = src | dst_local<<20   (requires n < 2^20)
// ---------------------------------------------------------------------------
__global__ void __launch_bounds__(256) bin_scatter_kernel(
        const int* __restrict__ ei, const int* __restrict__ flag,
        int* __restrict__ cnt, uint32_t* __restrict__ binned,
        long E, int NBIN) {
    const int part = blockIdx.x & (NPART - 1);
    const int f = *flag;
    const long stride = (long)gridDim.x * blockDim.x;
    for (long e = (long)blockIdx.x * blockDim.x + threadIdx.x; e < E; e += stride) {
        int s = fetch_idx(ei, e, f);
        int d = fetch_idx(ei, E + e, f);
        int r = part * NBIN + (d >> 8);
        int pos = atomicAdd(&cnt[r], 1);
        binned[(size_t)r * CAPPP + pos] = (uint32_t)s | ((uint32_t)(d & (PSIZE - 1)) << 20);
    }
}

// bin totals = sum over the 8 part counters
__global__ void bintot_kernel(const int* __restrict__ cnt, int* __restrict__ bin_tot,
                              int NBIN) {
    int b = blockIdx.x * blockDim.x + threadIdx.x;
    if (b < NBIN) {
        int s = 0;
#pragma unroll
        for (int p = 0; p < NPART; ++p) s += cnt[p * NBIN + b];
        bin_tot[b] = s;
    }
}

// generic single-block exclusive scan (reused for bin offsets)
__global__ void __launch_bounds__(1024) scan_kernel(const int* __restrict__ deg,
                                                    int* __restrict__ ofs, int n) {
    __shared__ int wsum[16];
    __shared__ int carry_s;
    __shared__ int chunk_tot;
    const int tid  = threadIdx.x;
    const int lane = tid & 63;
    const int wid  = tid >> 6;
    if (tid == 0) carry_s = 0;
    __syncthreads();
    const int CHUNK = 4096;
    for (int base = 0; base < n; base += CHUNK) {
        int idx = base + tid * 4;
        int v[4];
#pragma unroll
        for (int j = 0; j < 4; ++j) v[j] = (idx + j < n) ? deg[idx + j] : 0;
        int s1 = v[0] + v[1] + v[2] + v[3];
        int inc = s1;
#pragma unroll
        for (int d = 1; d < 64; d <<= 1) {
            int t = __shfl_up(inc, d, 64);
            if (lane >= d) inc += t;
        }
        if (lane == 63) wsum[wid] = inc;
        __syncthreads();
        if (wid == 0) {
            int ws = (lane < 16) ? wsum[lane] : 0;
            int winc = ws;
#pragma unroll
            for (int d = 1; d < 16; d <<= 1) {
                int t = __shfl_up(winc, d, 64);
                if (lane >= d) winc += t;
            }
            if (lane == 15) chunk_tot = winc;
            if (lane < 16) wsum[lane] = winc - ws;
        }
        __syncthreads();
        int excl = carry_s + wsum[wid] + (inc - s1);
        int run = excl;
#pragma unroll
        for (int j = 0; j < 4; ++j) {
            if (idx + j < n) ofs[idx + j] = run;
            run += v[j];
        }
        __syncthreads();
        if (tid == 0) carry_s += chunk_tot;
        __syncthreads();
    }
    if (tid == 0) ofs[n] = carry_s;
}

// ---------------------------------------------------------------------------
// CSR pass B: one block per bin. 8 waves, wave p reads sub-region (p,bin).
// LDS histogram -> scan -> scatter to col; emits ofs and dinv directly.
// ---------------------------------------------------------------------------
__global__ void __launch_bounds__(512) bin_build_kernel(
        const uint32_t* __restrict__ binned, const int* __restrict__ cnt,
        const int* __restrict__ bofs, int* __restrict__ ofs,
        float* __restrict__ dinv, int* __restrict__ col,
        int n, int NBIN, long E) {
    __shared__ int lcnt[PSIZE];
    __shared__ int lofs[PSIZE];
    __shared__ int lrank[PSIZE];
    __shared__ int wtot[4];
    const int b    = blockIdx.x;
    const int v0   = b * PSIZE;
    const int nn   = min(PSIZE, n - v0);
    const int tid  = threadIdx.x;
    const int wv   = tid >> 6;      // 0..7 = part
    const int lane = tid & 63;
    if (tid < PSIZE) { lcnt[tid] = 0; lrank[tid] = 0; }
    __syncthreads();
    const int r = wv * NBIN + b;
    const int c = cnt[r];
    const uint32_t* __restrict__ src = binned + (size_t)r * CAPPP;
    for (int i = lane; i < c; i += 64)
        atomicAdd(&lcnt[src[i] >> 20], 1);
    __syncthreads();
    if (tid < PSIZE) {               // 4-wave two-level scan of lcnt
        int v = lcnt[tid];
        int inc = v;
#pragma unroll
        for (int d = 1; d < 64; d <<= 1) {
            int t = __shfl_up(inc, d, 64);
            if (lane >= d) inc += t;
        }
        if (lane == 63) wtot[wv] = inc;
        lofs[tid] = inc - v;
    }
    __syncthreads();
    if (tid < PSIZE) {
        int add = 0;
#pragma unroll
        for (int k = 0; k < 4; ++k) if (k < wv) add += wtot[k];
        lofs[tid] += add;
    }
    __syncthreads();
    const int base = bofs[b];
    for (int i = lane; i < c; i += 64) {
        uint32_t v = src[i];
        int dl = (int)(v >> 20);
        int rk = atomicAdd(&lrank[dl], 1);
        col[base + lofs[dl] + rk] = (int)(v & 0xFFFFFu);
    }
    if (tid < nn) {
        ofs[v0 + tid]  = base + lofs[tid];
        dinv[v0 + tid] = rsqrtf((float)lcnt[tid] + 1.0f);
    }
    if (tid == 0 && v0 + nn == n) ofs[n] = (int)E;
}

// ---------------------------------------------------------------------------
// Weight prep: Wt[w] = transpose(W_w) split into bf16 hi + lo planes.
// ---------------------------------------------------------------------------
__global__ void __launch_bounds__(128) wprep_kernel(
        const float* __restrict__ W0, const float* __restrict__ W1,
        const float* __restrict__ W2, short* __restrict__ Wt) {
    const float* W = (blockIdx.x == 0) ? W0 : (blockIdx.x == 1) ? W1 : W2;
    short* hi = Wt + (size_t)blockIdx.x * 2 * HID * HID;
    short* lo = hi + HID * HID;
    __shared__ float Ws[64][129];
    const int t = threadIdx.x;
    for (int half = 0; half < 2; ++half) {
        const int kbase = half * 64;
#pragma unroll
        for (int it = 0; it < 16; ++it) {
            int idx = (t + it * 128) * 4;
            int k = idx >> 7, c = idx & 127;
            float4 v = *(const float4*)(W + (size_t)(kbase + k) * HID + c);
            Ws[k][c] = v.x; Ws[k][c + 1] = v.y; Ws[k][c + 2] = v.z; Ws[k][c + 3] = v.w;
        }
        __syncthreads();
        for (int it = 0; it < 64; ++it) {
            int k2 = t & 63;
            int c  = (t >> 6) + it * 2;
            float w = Ws[k2][c];
            short h = f2bf(w);
            hi[(size_t)c * HID + kbase + k2] = h;
            lo[(size_t)c * HID + kbase + k2] = f2bf(w - bf2f(h));
        }
        __syncthreads();
    }
}

// ---------------------------------------------------------------------------
// hs = bf16( (A @ W) * dinv[:,None] ) — MFMA bf16, LDS-free, split-W hi+lo.
// ---------------------------------------------------------------------------
template<bool AFP32>
__global__ void __launch_bounds__(256) gemm_hs_kernel(
        const void* __restrict__ Ap, const short* __restrict__ Wt,
        const float* __restrict__ dinv, short* __restrict__ hs, int n) {
    const short* __restrict__ Bh = Wt;
    const short* __restrict__ Bl = Wt + HID * HID;
    const int tid = threadIdx.x;
    const int w  = tid >> 6;
    const int l  = tid & 63;
    const int lr = l & 15;
    const int kq = l >> 4;
    const int r0 = blockIdx.x * 128;

    f32x4 acc[8][2] = {};
    const int col0 = w * 32 + lr;
    const int col1 = w * 32 + 16 + lr;

    const float* Af = (const float*)Ap;
    const short* Ab = (const short*)Ap;

#pragma unroll
    for (int ks = 0; ks < 4; ++ks) {
        const int k0 = ks * 32 + kq * 8;
        bf16x8 a[8];
#pragma unroll
        for (int rf = 0; rf < 8; ++rf) {
            int row = r0 + rf * 16 + lr;
            if (row >= n) row = n - 1;
            if (AFP32) {
                const float* ap = Af + (size_t)row * HID + k0;
                float4 f0 = *(const float4*)ap;
                float4 f1 = *(const float4*)(ap + 4);
                bf16x8 tv;
                tv[0] = f2bf(f0.x); tv[1] = f2bf(f0.y); tv[2] = f2bf(f0.z); tv[3] = f2bf(f0.w);
                tv[4] = f2bf(f1.x); tv[5] = f2bf(f1.y); tv[6] = f2bf(f1.z); tv[7] = f2bf(f1.w);
                a[rf] = tv;
            } else {
                a[rf] = *(const bf16x8*)(Ab + (size_t)row * HID + k0);
            }
        }
        bf16x8 bh0 = *(const bf16x8*)(Bh + (size_t)col0 * HID + k0);
        bf16x8 bh1 = *(const bf16x8*)(Bh + (size_t)col1 * HID + k0);
        bf16x8 bl0 = *(const bf16x8*)(Bl + (size_t)col0 * HID + k0);
        bf16x8 bl1 = *(const bf16x8*)(Bl + (size_t)col1 * HID + k0);
#pragma unroll
        for (int rf = 0; rf < 8; ++rf) {
            acc[rf][0] = __builtin_amdgcn_mfma_f32_16x16x32_bf16(a[rf], bh0, acc[rf][0], 0, 0, 0);
            acc[rf][1] = __builtin_amdgcn_mfma_f32_16x16x32_bf16(a[rf], bh1, acc[rf][1], 0, 0, 0);
            acc[rf][0] = __builtin_amdgcn_mfma_f32_16x16x32_bf16(a[rf], bl0, acc[rf][0], 0, 0, 0);
            acc[rf][1] = __builtin_amdgcn_mfma_f32_16x16x32_bf16(a[rf], bl1, acc[rf][1], 0, 0, 0);
        }
    }
#pragma unroll
    for (int rf = 0; rf < 8; ++rf) {
#pragma unroll
        for (int rg = 0; rg < 4; ++rg) {
            int row = r0 + rf * 16 + kq * 4 + rg;
            if (row < n) {
                float dn = dinv[row];
                hs[(size_t)row * HID + col0] = f2bf(acc[rf][0][rg] * dn);
                hs[(size_t)row * HID + col1] = f2bf(acc[rf][1][rg] * dn);
            }
        }
    }
}

// ---------------------------------------------------------------------------
// out[d] = maybe_relu( dinv[d] * (hs[d] + sum_{e->d} hs[src]) + bias )  (bf16)
// one wave per node, lane = 2 channels, 8 outstanding gathers
// ---------------------------------------------------------------------------
__global__ void __launch_bounds__(256) agg_kernel(
        const short* __restrict__ hs, const float* __restrict__ dinv,
        const int* __restrict__ ofs, const int* __restrict__ col,
        const float* __restrict__ bias, short* __restrict__ out,
        int n, int do_relu) {
    int node = blockIdx.x * 4 + (threadIdx.x >> 6);
    if (node >= n) return;
    int lane = threadIdx.x & 63;
    const uint32_t* __restrict__ h2 = (const uint32_t*)hs;

    uint32_t sv = h2[(size_t)node * 64 + lane];
    float ax = bflo(sv), ay = bfhi(sv);
    int e0 = ofs[node], e1 = ofs[node + 1];
    int e = e0;
    for (; e + 8 <= e1; e += 8) {
        int s0 = col[e],     s1 = col[e + 1], s2 = col[e + 2], s3 = col[e + 3];
        int s4 = col[e + 4], s5 = col[e + 5], s6 = col[e + 6], s7 = col[e + 7];
        uint32_t v0 = h2[(size_t)s0 * 64 + lane];
        uint32_t v1 = h2[(size_t)s1 * 64 + lane];
        uint32_t v2 = h2[(size_t)s2 * 64 + lane];
        uint32_t v3 = h2[(size_t)s3 * 64 + lane];
        uint32_t v4 = h2[(size_t)s4 * 64 + lane];
        uint32_t v5 = h2[(size_t)s5 * 64 + lane];
        uint32_t v6 = h2[(size_t)s6 * 64 + lane];
        uint32_t v7 = h2[(size_t)s7 * 64 + lane];
        ax += bflo(v0) + bflo(v1) + bflo(v2) + bflo(v3)
            + bflo(v4) + bflo(v5) + bflo(v6) + bflo(v7);
        ay += bfhi(v0) + bfhi(v1) + bfhi(v2) + bfhi(v3)
            + bfhi(v4) + bfhi(v5) + bfhi(v6) + bfhi(v7);
    }
    for (; e < e1; ++e) {
        uint32_t v = h2[(size_t)col[e] * 64 + lane];
        ax += bflo(v); ay += bfhi(v);
    }
    float dn = dinv[node];
    float2 b = ((const float2*)bias)[lane];
    float ox = fmaf(ax, dn, b.x);
    float oy = fmaf(ay, dn, b.y);
    if (do_relu) { ox = fmaxf(ox, 0.f); oy = fmaxf(oy, 0.f); }
    uint32_t pk = (uint32_t)(uint16_t)f2bf(ox) | ((uint32_t)(uint16_t)f2bf(oy) << 16);
    ((uint32_t*)out)[(size_t)node * 64 + lane] = pk;
}

// ---------------------------------------------------------------------------
// pooling + MLP head
// ---------------------------------------------------------------------------
__global__ void boundary_kernel(const int* __restrict__ batch, const int* __restrict__ flag,
                                int* __restrict__ gstart, int n) {
    int i = blockIdx.x * blockDim.x + threadIdx.x;
    if (i >= n) return;
    int f = *flag;
    int b  = fetch_idx(batch, i, f);
    int bp = (i == 0) ? -1 : fetch_idx(batch, i - 1, f);
    for (int g = bp + 1; g <= b; ++g) gstart[g] = i;
    if (i == n - 1) {
        for (int g = b + 1; g <= NGRAPH; ++g) gstart[g] = n;
    }
}

__global__ void __launch_bounds__(128) pool_kernel(const short* __restrict__ h,
                                                   const int* __restrict__ gstart,
                                                   float* __restrict__ pooled) {
    int g = blockIdx.x, c = threadIdx.x;
    int s = gstart[g], e = gstart[g + 1];
    float acc = 0.f;
    int i = s;
    for (; i + 4 <= e; i += 4) {
        acc += bf2f(h[(size_t)i * HID + c]) + bf2f(h[(size_t)(i + 1) * HID + c])
             + bf2f(h[(size_t)(i + 2) * HID + c]) + bf2f(h[(size_t)(i + 3) * HID + c]);
    }
    for (; i < e; ++i) acc += bf2f(h[(size_t)i * HID + c]);
    float cnt = (float)(e - s);
    pooled[g * HID + c] = acc / fmaxf(cnt, 1.f);
}

__global__ void __launch_bounds__(128) mlp_kernel(
        const float* __restrict__ pooled,
        const float* __restrict__ W1, const float* __restrict__ b1,
        const float* __restrict__ W2, const float* __restrict__ b2,
        float* __restrict__ out) {
    __shared__ float p[HID];
    __shared__ float hid[HID];
    int g = blockIdx.x, c = threadIdx.x;
    p[c] = pooled[g * HID + c];
    __syncthreads();
    float a = b1[c];
#pragma unroll 8
    for (int k = 0; k < HID; ++k) a = fmaf(p[k], W1[k * HID + c], a);
    hid[c] = fmaxf(a, 0.f);
    __syncthreads();
    if (c < OUTC) {
        float o = b2[c];
#pragma unroll 8
        for (int k = 0; k < HID; ++k) o = fmaf(hid[k], W2[k * OUTC + c], o);
        out[g * OUTC + c] = o;
    }
}

// ---------------------------------------------------------------------------
extern "C" void kernel_launch(void* const* d_in, const int* in_sizes, int n_in,
                              void* d_out, int out_size, void* d_ws, size_t ws_size,
                              hipStream_t stream) {
    const float* x   = (const float*)d_in[0];
    const int*   ei  = (const int*)d_in[1];
    const int*   bat = (const int*)d_in[2];
    const float* Wc0 = (const float*)d_in[3];
    const float* bc0 = (const float*)d_in[4];
    const float* Wc1 = (const float*)d_in[5];
    const float* bc1 = (const float*)d_in[6];
    const float* Wc2 = (const float*)d_in[7];
    const float* bc2 = (const float*)d_in[8];
    const float* W1  = (const float*)d_in[9];
    const float* b1  = (const float*)d_in[10];
    const float* W2  = (const float*)d_in[11];
    const float* b2  = (const float*)d_in[12];
    float* out = (float*)d_out;

    const int  n = in_sizes[0] / HID;           // 100000  (< 2^20, required by packing)
    const long E = in_sizes[1] / 2;
    const int  NBIN = (n + PSIZE - 1) / PSIZE;  // 391

    char* w = (char*)d_ws;
    size_t off = 0;
    auto carve = [&](size_t bytes) {
        void* p = w + off;
        off += (bytes + 255) & ~(size_t)255;
        return p;
    };
    int*   flag    = (int*)carve(4);
    int*   cnt     = (int*)carve((size_t)NPART * NBIN * 4);
    int*   bin_tot = (int*)carve((size_t)NBIN * 4);
    int*   bofs    = (int*)carve((size_t)(NBIN + 1) * 4);
    int*   ofs     = (int*)carve((size_t)(n + 1) * 4);
    float* dinv    = (float*)carve((size_t)n * 4);
    int*   gstart  = (int*)carve((NGRAPH + 1) * 4);
    int*   col     = (int*)carve((size_t)E * 4);
    short* Wt      = (short*)carve((size_t)3 * 2 * HID * HID * 2);
    short* hs      = (short*)carve((size_t)n * HID * 2);
    short* h       = (short*)carve((size_t)n * HID * 2);
    float* pooled  = (float*)carve((size_t)NGRAPH * HID * 4);
    uint32_t* binned = (uint32_t*)h;  // 8*NBIN*CAPPP*4 = 12.8 MB <= 25.6 MB, dead before h is written

    hipMemsetAsync(cnt, 0, (size_t)NPART * NBIN * 4, stream);

    detect64_kernel<<<1, 64, 0, stream>>>(ei, flag);

    bin_scatter_kernel<<<2048, 256, 0, stream>>>(ei, flag, cnt, binned, E, NBIN);
    bintot_kernel<<<(NBIN + 255) / 256, 256, 0, stream>>>(cnt, bin_tot, NBIN);
    scan_kernel<<<1, 1024, 0, stream>>>(bin_tot, bofs, NBIN);
    bin_build_kernel<<<NBIN, 512, 0, stream>>>(binned, cnt, bofs, ofs, dinv, col, n, NBIN, E);
    wprep_kernel<<<3, 128, 0, stream>>>(Wc0, Wc1, Wc2, Wt);

    const int gb = (n + 127) / 128;
    const int ab = (n + 3) / 4;
    const size_t WSTRIDE = (size_t)2 * HID * HID;
    // layer 0
    gemm_hs_kernel<true><<<gb, 256, 0, stream>>>(x, Wt, dinv, hs, n);
    agg_kernel<<<ab, 256, 0, stream>>>(hs, dinv, ofs, col, bc0, h, n, 1);
    // layer 1
    gemm_hs_kernel<false><<<gb, 256, 0, stream>>>(h, Wt + WSTRIDE, dinv, hs, n);
    agg_kernel<<<ab, 256, 0, stream>>>(hs, dinv, ofs, col, bc1, h, n, 1);
    // layer 2 (no relu)
    gemm_hs_kernel<false><<<gb, 256, 0, stream>>>(h, Wt + 2 * WSTRIDE, dinv, hs, n);
    agg_kernel<<<ab, 256, 0, stream>>>(hs, dinv, ofs, col, bc2, h, n, 0);

    boundary_kernel<<<(n + 255) / 256, 256, 0, stream>>>(bat, flag, gstart, n);
    pool_kernel<<<NGRAPH, 128, 0, stream>>>(h, gstart, pooled);
    mlp_kernel<<<NGRAPH, 128, 0, stream>>>(pooled, W1, b1, W2, b2, out);
}

// Round 6
// 461.533 us; speedup vs baseline: 1.6824x; 1.1781x over previous
//
#include <hip/hip_runtime.h>
#include <hip/hip_bf16.h>
#include <stdint.h>

#define HID     128
#define OUTC    10
#define NGRAPH  512
#define NGROUP  64         // writer groups (low 3 bits ~ XCD)
#define PSIZE   256        // nodes per bin
#define CAP     160        // entries per (group,bin) sub-region (mean 64, 12 sd headroom)

using bf16x8 = __attribute__((ext_vector_type(8))) short;
using f32x4  = __attribute__((ext_vector_type(4))) float;

__device__ __forceinline__ short f2bf(float f) {
    __hip_bfloat16 h = __float2bfloat16(f);
    return *reinterpret_cast<short*>(&h);
}
__device__ __forceinline__ float bf2f(short s) {
    union { uint32_t u; float f; } x; x.u = ((uint32_t)(uint16_t)s) << 16; return x.f;
}
__device__ __forceinline__ float bflo(uint32_t v) {
    union { uint32_t u; float f; } x; x.u = v << 16; return x.f;
}
__device__ __forceinline__ float bfhi(uint32_t v) {
    union { uint32_t u; float f; } x; x.u = v & 0xffff0000u; return x.f;
}

// ---------------------------------------------------------------------------
// int64-vs-int32 layout detection (wave-parallel)
// ---------------------------------------------------------------------------
__global__ void detect64_kernel(const int* __restrict__ ei, int* __restrict__ flag) {
    int lane = threadIdx.x & 63;
    int v = ei[2 * lane + 1];
    unsigned long long b = __ballot(v == 0);
    if (threadIdx.x == 0) *flag = (b == ~0ULL) ? 1 : 0;
}

__device__ __forceinline__ int fetch_idx(const int* __restrict__ p, long j, int f64) {
    return p[f64 ? (j << 1) : j];
}

// ---------------------------------------------------------------------------
// CSR pass A: writer-partitioned bin scatter, 64 writer groups.
// group = blockIdx&63 (low 3 bits ~ XCD round-robin -> writer locality).
// 25K counters cut same-address atomic contention to ~64 increments each.
// entry = src | dst_local<<20   (requires n < 2^20)
// ---------------------------------------------------------------------------
__global__ void __launch_bounds__(256) bin_scatter_kernel(
        const int* __restrict__ ei, const int* __restrict__ flag,
        int* __restrict__ cnt, uint32_t* __restrict__ binned,
        long E, int NBIN, int NBINP) {
    const int group = blockIdx.x & (NGROUP - 1);
    const int f = *flag;
    const long stride = (long)gridDim.x * blockDim.x;
    for (long e = (long)blockIdx.x * blockDim.x + threadIdx.x; e < E; e += stride) {
        int s = fetch_idx(ei, e, f);
        int d = fetch_idx(ei, E + e, f);
        int b = d >> 8;
        int pos = atomicAdd(&cnt[group * NBINP + b], 1);
        if (pos < CAP)
            binned[((size_t)group * NBIN + b) * CAP + pos] =
                (uint32_t)s | ((uint32_t)(d & (PSIZE - 1)) << 20);
    }
}

// bin totals = sum over the 64 group counters
__global__ void bintot_kernel(const int* __restrict__ cnt, int* __restrict__ bin_tot,
                              int NBIN, int NBINP) {
    int b = blockIdx.x * blockDim.x + threadIdx.x;
    if (b < NBIN) {
        int s = 0;
#pragma unroll
        for (int g = 0; g < NGROUP; ++g) s += cnt[g * NBINP + b];
        bin_tot[b] = s;
    }
}

// generic single-block exclusive scan (bin offsets)
__global__ void __launch_bounds__(1024) scan_kernel(const int* __restrict__ deg,
                                                    int* __restrict__ ofs, int n) {
    __shared__ int wsum[16];
    __shared__ int carry_s;
    __shared__ int chunk_tot;
    const int tid  = threadIdx.x;
    const int lane = tid & 63;
    const int wid  = tid >> 6;
    if (tid == 0) carry_s = 0;
    __syncthreads();
    const int CHUNK = 4096;
    for (int base = 0; base < n; base += CHUNK) {
        int idx = base + tid * 4;
        int v[4];
#pragma unroll
        for (int j = 0; j < 4; ++j) v[j] = (idx + j < n) ? deg[idx + j] : 0;
        int s1 = v[0] + v[1] + v[2] + v[3];
        int inc = s1;
#pragma unroll
        for (int d = 1; d < 64; d <<= 1) {
            int t = __shfl_up(inc, d, 64);
            if (lane >= d) inc += t;
        }
        if (lane == 63) wsum[wid] = inc;
        __syncthreads();
        if (wid == 0) {
            int ws = (lane < 16) ? wsum[lane] : 0;
            int winc = ws;
#pragma unroll
            for (int d = 1; d < 16; d <<= 1) {
                int t = __shfl_up(winc, d, 64);
                if (lane >= d) winc += t;
            }
            if (lane == 15) chunk_tot = winc;
            if (lane < 16) wsum[lane] = winc - ws;
        }
        __syncthreads();
        int excl = carry_s + wsum[wid] + (inc - s1);
        int run = excl;
#pragma unroll
        for (int j = 0; j < 4; ++j) {
            if (idx + j < n) ofs[idx + j] = run;
            run += v[j];
        }
        __syncthreads();
        if (tid == 0) carry_s += chunk_tot;
        __syncthreads();
    }
    if (tid == 0) ofs[n] = carry_s;
}

// ---------------------------------------------------------------------------
// CSR pass B: one block per bin. 8 waves; wave wv handles sub-regions
// wv, wv+8, ... LDS histogram -> scan -> scatter; emits ofs + dinv.
// ---------------------------------------------------------------------------
__global__ void __launch_bounds__(512) bin_build_kernel(
        const uint32_t* __restrict__ binned, const int* __restrict__ cnt,
        const int* __restrict__ bofs, int* __restrict__ ofs,
        float* __restrict__ dinv, int* __restrict__ col,
        int n, int NBIN, int NBINP, long E) {
    __shared__ int lcnt[PSIZE];
    __shared__ int lofs[PSIZE];
    __shared__ int lrank[PSIZE];
    __shared__ int wtot[4];
    const int b    = blockIdx.x;
    const int v0   = b * PSIZE;
    const int nn   = min(PSIZE, n - v0);
    const int tid  = threadIdx.x;
    const int wv   = tid >> 6;      // 0..7
    const int lane = tid & 63;
    if (tid < PSIZE) { lcnt[tid] = 0; lrank[tid] = 0; }
    __syncthreads();
#pragma unroll
    for (int sg = wv; sg < NGROUP; sg += 8) {
        const int c = min(cnt[sg * NBINP + b], CAP);
        const uint32_t* __restrict__ src = binned + ((size_t)sg * NBIN + b) * CAP;
        for (int i = lane; i < c; i += 64)
            atomicAdd(&lcnt[src[i] >> 20], 1);
    }
    __syncthreads();
    if (tid < PSIZE) {               // 4-wave two-level scan of lcnt
        int v = lcnt[tid];
        int inc = v;
#pragma unroll
        for (int d = 1; d < 64; d <<= 1) {
            int t = __shfl_up(inc, d, 64);
            if (lane >= d) inc += t;
        }
        if (lane == 63) wtot[wv] = inc;
        lofs[tid] = inc - v;
    }
    __syncthreads();
    if (tid < PSIZE) {
        int add = 0;
#pragma unroll
        for (int k = 0; k < 4; ++k) if (k < wv) add += wtot[k];
        lofs[tid] += add;
    }
    __syncthreads();
    const int base = bofs[b];
#pragma unroll
    for (int sg = wv; sg < NGROUP; sg += 8) {
        const int c = min(cnt[sg * NBINP + b], CAP);
        const uint32_t* __restrict__ src = binned + ((size_t)sg * NBIN + b) * CAP;
        for (int i = lane; i < c; i += 64) {
            uint32_t v = src[i];
            int dl = (int)(v >> 20);
            int rk = atomicAdd(&lrank[dl], 1);
            col[base + lofs[dl] + rk] = (int)(v & 0xFFFFFu);
        }
    }
    if (tid < nn) {
        ofs[v0 + tid]  = base + lofs[tid];
        dinv[v0 + tid] = rsqrtf((float)lcnt[tid] + 1.0f);
    }
    if (tid == 0 && v0 + nn == n) ofs[n] = (int)E;
}

// ---------------------------------------------------------------------------
// Weight prep: Wt[w] = transpose(W_w) split into bf16 hi + lo planes.
// ---------------------------------------------------------------------------
__global__ void __launch_bounds__(128) wprep_kernel(
        const float* __restrict__ W0, const float* __restrict__ W1,
        const float* __restrict__ W2, short* __restrict__ Wt) {
    const float* W = (blockIdx.x == 0) ? W0 : (blockIdx.x == 1) ? W1 : W2;
    short* hi = Wt + (size_t)blockIdx.x * 2 * HID * HID;
    short* lo = hi + HID * HID;
    __shared__ float Ws[64][129];
    const int t = threadIdx.x;
    for (int half = 0; half < 2; ++half) {
        const int kbase = half * 64;
#pragma unroll
        for (int it = 0; it < 16; ++it) {
            int idx = (t + it * 128) * 4;
            int k = idx >> 7, c = idx & 127;
            float4 v = *(const float4*)(W + (size_t)(kbase + k) * HID + c);
            Ws[k][c] = v.x; Ws[k][c + 1] = v.y; Ws[k][c + 2] = v.z; Ws[k][c + 3] = v.w;
        }
        __syncthreads();
        for (int it = 0; it < 64; ++it) {
            int k2 = t & 63;
            int c  = (t >> 6) + it * 2;
            float w = Ws[k2][c];
            short h = f2bf(w);
            hi[(size_t)c * HID + kbase + k2] = h;
            lo[(size_t)c * HID + kbase + k2] = f2bf(w - bf2f(h));
        }
        __syncthreads();
    }
}

// ---------------------------------------------------------------------------
// hs = bf16( (A @ W) * dinv[:,None] ) — MFMA bf16, LDS-free, split-W hi+lo.
// ---------------------------------------------------------------------------
template<bool AFP32>
__global__ void __launch_bounds__(256) gemm_hs_kernel(
        const void* __restrict__ Ap, const short* __restrict__ Wt,
        const float* __restrict__ dinv, short* __restrict__ hs, int n) {
    const short* __restrict__ Bh = Wt;
    const short* __restrict__ Bl = Wt + HID * HID;
    const int tid = threadIdx.x;
    const int w  = tid >> 6;
    const int l  = tid & 63;
    const int lr = l & 15;
    const int kq = l >> 4;
    const int r0 = blockIdx.x * 128;

    f32x4 acc[8][2] = {};
    const int col0 = w * 32 + lr;
    const int col1 = w * 32 + 16 + lr;

    const float* Af = (const float*)Ap;
    const short* Ab = (const short*)Ap;

#pragma unroll
    for (int ks = 0; ks < 4; ++ks) {
        const int k0 = ks * 32 + kq * 8;
        bf16x8 a[8];
#pragma unroll
        for (int rf = 0; rf < 8; ++rf) {
            int row = r0 + rf * 16 + lr;
            if (row >= n) row = n - 1;
            if (AFP32) {
                const float* ap = Af + (size_t)row * HID + k0;
                float4 f0 = *(const float4*)ap;
                float4 f1 = *(const float4*)(ap + 4);
                bf16x8 tv;
                tv[0] = f2bf(f0.x); tv[1] = f2bf(f0.y); tv[2] = f2bf(f0.z); tv[3] = f2bf(f0.w);
                tv[4] = f2bf(f1.x); tv[5] = f2bf(f1.y); tv[6] = f2bf(f1.z); tv[7] = f2bf(f1.w);
                a[rf] = tv;
            } else {
                a[rf] = *(const bf16x8*)(Ab + (size_t)row * HID + k0);
            }
        }
        bf16x8 bh0 = *(const bf16x8*)(Bh + (size_t)col0 * HID + k0);
        bf16x8 bh1 = *(const bf16x8*)(Bh + (size_t)col1 * HID + k0);
        bf16x8 bl0 = *(const bf16x8*)(Bl + (size_t)col0 * HID + k0);
        bf16x8 bl1 = *(const bf16x8*)(Bl + (size_t)col1 * HID + k0);
#pragma unroll
        for (int rf = 0; rf < 8; ++rf) {
            acc[rf][0] = __builtin_amdgcn_mfma_f32_16x16x32_bf16(a[rf], bh0, acc[rf][0], 0, 0, 0);
            acc[rf][1] = __builtin_amdgcn_mfma_f32_16x16x32_bf16(a[rf], bh1, acc[rf][1], 0, 0, 0);
            acc[rf][0] = __builtin_amdgcn_mfma_f32_16x16x32_bf16(a[rf], bl0, acc[rf][0], 0, 0, 0);
            acc[rf][1] = __builtin_amdgcn_mfma_f32_16x16x32_bf16(a[rf], bl1, acc[rf][1], 0, 0, 0);
        }
    }
#pragma unroll
    for (int rf = 0; rf < 8; ++rf) {
#pragma unroll
        for (int rg = 0; rg < 4; ++rg) {
            int row = r0 + rf * 16 + kq * 4 + rg;
            if (row < n) {
                float dn = dinv[row];
                hs[(size_t)row * HID + col0] = f2bf(acc[rf][0][rg] * dn);
                hs[(size_t)row * HID + col1] = f2bf(acc[rf][1][rg] * dn);
            }
        }
    }
}

// ---------------------------------------------------------------------------
// out[d] = maybe_relu( dinv[d] * (hs[d] + sum_{e->d} hs[src]) + bias )  (bf16)
// one wave per node, lane = 2 channels, 8 outstanding gathers
// ---------------------------------------------------------------------------
__global__ void __launch_bounds__(256) agg_kernel(
        const short* __restrict__ hs, const float* __restrict__ dinv,
        const int* __restrict__ ofs, const int* __restrict__ col,
        const float* __restrict__ bias, short* __restrict__ out,
        int n, int do_relu) {
    int node = blockIdx.x * 4 + (threadIdx.x >> 6);
    if (node >= n) return;
    int lane = threadIdx.x & 63;
    const uint32_t* __restrict__ h2 = (const uint32_t*)hs;

    uint32_t sv = h2[(size_t)node * 64 + lane];
    float ax = bflo(sv), ay = bfhi(sv);
    int e0 = ofs[node], e1 = ofs[node + 1];
    int e = e0;
    for (; e + 8 <= e1; e += 8) {
        int s0 = col[e],     s1 = col[e + 1], s2 = col[e + 2], s3 = col[e + 3];
        int s4 = col[e + 4], s5 = col[e + 5], s6 = col[e + 6], s7 = col[e + 7];
        uint32_t v0 = h2[(size_t)s0 * 64 + lane];
        uint32_t v1 = h2[(size_t)s1 * 64 + lane];
        uint32_t v2 = h2[(size_t)s2 * 64 + lane];
        uint32_t v3 = h2[(size_t)s3 * 64 + lane];
        uint32_t v4 = h2[(size_t)s4 * 64 + lane];
        uint32_t v5 = h2[(size_t)s5 * 64 + lane];
        uint32_t v6 = h2[(size_t)s6 * 64 + lane];
        uint32_t v7 = h2[(size_t)s7 * 64 + lane];
        ax += bflo(v0) + bflo(v1) + bflo(v2) + bflo(v3)
            + bflo(v4) + bflo(v5) + bflo(v6) + bflo(v7);
        ay += bfhi(v0) + bfhi(v1) + bfhi(v2) + bfhi(v3)
            + bfhi(v4) + bfhi(v5) + bfhi(v6) + bfhi(v7);
    }
    for (; e < e1; ++e) {
        uint32_t v = h2[(size_t)col[e] * 64 + lane];
        ax += bflo(v); ay += bfhi(v);
    }
    float dn = dinv[node];
    float2 b = ((const float2*)bias)[lane];
    float ox = fmaf(ax, dn, b.x);
    float oy = fmaf(ay, dn, b.y);
    if (do_relu) { ox = fmaxf(ox, 0.f); oy = fmaxf(oy, 0.f); }
    uint32_t pk = (uint32_t)(uint16_t)f2bf(ox) | ((uint32_t)(uint16_t)f2bf(oy) << 16);
    ((uint32_t*)out)[(size_t)node * 64 + lane] = pk;
}

// ---------------------------------------------------------------------------
// pooling + MLP head
// ---------------------------------------------------------------------------
__global__ void boundary_kernel(const int* __restrict__ batch, const int* __restrict__ flag,
                                int* __restrict__ gstart, int n) {
    int i = blockIdx.x * blockDim.x + threadIdx.x;
    if (i >= n) return;
    int f = *flag;
    int b  = fetch_idx(batch, i, f);
    int bp = (i == 0) ? -1 : fetch_idx(batch, i - 1, f);
    for (int g = bp + 1; g <= b; ++g) gstart[g] = i;
    if (i == n - 1) {
        for (int g = b + 1; g <= NGRAPH; ++g) gstart[g] = n;
    }
}

__global__ void __launch_bounds__(128) pool_kernel(const short* __restrict__ h,
                                                   const int* __restrict__ gstart,
                                                   float* __restrict__ pooled) {
    int g = blockIdx.x, c = threadIdx.x;
    int s = gstart[g], e = gstart[g + 1];
    float acc = 0.f;
    int i = s;
    for (; i + 4 <= e; i += 4) {
        acc += bf2f(h[(size_t)i * HID + c]) + bf2f(h[(size_t)(i + 1) * HID + c])
             + bf2f(h[(size_t)(i + 2) * HID + c]) + bf2f(h[(size_t)(i + 3) * HID + c]);
    }
    for (; i < e; ++i) acc += bf2f(h[(size_t)i * HID + c]);
    float cnt = (float)(e - s);
    pooled[g * HID + c] = acc / fmaxf(cnt, 1.f);
}

__global__ void __launch_bounds__(128) mlp_kernel(
        const float* __restrict__ pooled,
        const float* __restrict__ W1, const float* __restrict__ b1,
        const float* __restrict__ W2, const float* __restrict__ b2,
        float* __restrict__ out) {
    __shared__ float p[HID];
    __shared__ float hid[HID];
    int g = blockIdx.x, c = threadIdx.x;
    p[c] = pooled[g * HID + c];
    __syncthreads();
    float a = b1[c];
#pragma unroll 8
    for (int k = 0; k < HID; ++k) a = fmaf(p[k], W1[k * HID + c], a);
    hid[c] = fmaxf(a, 0.f);
    __syncthreads();
    if (c < OUTC) {
        float o = b2[c];
#pragma unroll 8
        for (int k = 0; k < HID; ++k) o = fmaf(hid[k], W2[k * OUTC + c], o);
        out[g * OUTC + c] = o;
    }
}

// ---------------------------------------------------------------------------
extern "C" void kernel_launch(void* const* d_in, const int* in_sizes, int n_in,
                              void* d_out, int out_size, void* d_ws, size_t ws_size,
                              hipStream_t stream) {
    const float* x   = (const float*)d_in[0];
    const int*   ei  = (const int*)d_in[1];
    const int*   bat = (const int*)d_in[2];
    const float* Wc0 = (const float*)d_in[3];
    const float* bc0 = (const float*)d_in[4];
    const float* Wc1 = (const float*)d_in[5];
    const float* bc1 = (const float*)d_in[6];
    const float* Wc2 = (const float*)d_in[7];
    const float* bc2 = (const float*)d_in[8];
    const float* W1  = (const float*)d_in[9];
    const float* b1  = (const float*)d_in[10];
    const float* W2  = (const float*)d_in[11];
    const float* b2  = (const float*)d_in[12];
    float* out = (float*)d_out;

    const int  n = in_sizes[0] / HID;             // 100000 (< 2^20)
    const long E = in_sizes[1] / 2;
    const int  NBIN  = (n + PSIZE - 1) / PSIZE;   // 391
    const int  NBINP = (NBIN + 15) & ~15;         // 400: per-group counters line-aligned

    char* w = (char*)d_ws;
    size_t off = 0;
    auto carve = [&](size_t bytes) {
        void* p = w + off;
        off += (bytes + 255) & ~(size_t)255;
        return p;
    };
    int*   flag    = (int*)carve(4);
    int*   cnt     = (int*)carve((size_t)NGROUP * NBINP * 4);
    int*   bin_tot = (int*)carve((size_t)NBIN * 4);
    int*   bofs    = (int*)carve((size_t)(NBIN + 1) * 4);
    int*   ofs     = (int*)carve((size_t)(n + 1) * 4);
    float* dinv    = (float*)carve((size_t)n * 4);
    int*   gstart  = (int*)carve((NGRAPH + 1) * 4);
    int*   col     = (int*)carve((size_t)E * 4);
    short* Wt      = (short*)carve((size_t)3 * 2 * HID * HID * 2);
    short* hs      = (short*)carve((size_t)n * HID * 2);
    short* h       = (short*)carve((size_t)n * HID * 2);
    float* pooled  = (float*)carve((size_t)NGRAPH * HID * 4);
    uint32_t* binned = (uint32_t*)h;  // 64*391*160*4 = 16.0 MB <= 25.6 MB (h), dead before h written

    hipMemsetAsync(cnt, 0, (size_t)NGROUP * NBINP * 4, stream);

    detect64_kernel<<<1, 64, 0, stream>>>(ei, flag);

    bin_scatter_kernel<<<2048, 256, 0, stream>>>(ei, flag, cnt, binned, E, NBIN, NBINP);
    bintot_kernel<<<(NBIN + 255) / 256, 256, 0, stream>>>(cnt, bin_tot, NBIN, NBINP);
    scan_kernel<<<1, 1024, 0, stream>>>(bin_tot, bofs, NBIN);
    bin_build_kernel<<<NBIN, 512, 0, stream>>>(binned, cnt, bofs, ofs, dinv, col,
                                               n, NBIN, NBINP, E);
    wprep_kernel<<<3, 128, 0, stream>>>(Wc0, Wc1, Wc2, Wt);

    const int gb = (n + 127) / 128;
    const int ab = (n + 3) / 4;
    const size_t WSTRIDE = (size_t)2 * HID * HID;
    // layer 0
    gemm_hs_kernel<true><<<gb, 256, 0, stream>>>(x, Wt, dinv, hs, n);
    agg_kernel<<<ab, 256, 0, stream>>>(hs, dinv, ofs, col, bc0, h, n, 1);
    // layer 1
    gemm_hs_kernel<false><<<gb, 256, 0, stream>>>(h, Wt + WSTRIDE, dinv, hs, n);
    agg_kernel<<<ab, 256, 0, stream>>>(hs, dinv, ofs, col, bc1, h, n, 1);
    // layer 2 (no relu)
    gemm_hs_kernel<false><<<gb, 256, 0, stream>>>(h, Wt + 2 * WSTRIDE, dinv, hs, n);
    agg_kernel<<<ab, 256, 0, stream>>>(hs, dinv, ofs, col, bc2, h, n, 0);

    boundary_kernel<<<(n + 255) / 256, 256, 0, stream>>>(bat, flag, gstart, n);
    pool_kernel<<<NGRAPH, 128, 0, stream>>>(h, gstart, pooled);
    mlp_kernel<<<NGRAPH, 128, 0, stream>>>(pooled, W1, b1, W2, b2, out);
}

// Round 7
// 435.224 us; speedup vs baseline: 1.7841x; 1.0604x over previous
//
#include <hip/hip_runtime.h>
#include <hip/hip_bf16.h>
#include <stdint.h>

#define HID     128
#define OUTC    10
#define NGRAPH  512
#define NGROUP  64         // writer groups (low 3 bits ~ XCD)
#define PSIZE   256        // nodes per bin
#define CAP     160        // entries per (group,bin) sub-region (mean 64, 12 sd headroom)

using bf16x8 = __attribute__((ext_vector_type(8))) short;
using f32x4  = __attribute__((ext_vector_type(4))) float;

__device__ __forceinline__ short f2bf(float f) {
    __hip_bfloat16 h = __float2bfloat16(f);
    return *reinterpret_cast<short*>(&h);
}
__device__ __forceinline__ float bf2f(short s) {
    union { uint32_t u; float f; } x; x.u = ((uint32_t)(uint16_t)s) << 16; return x.f;
}
__device__ __forceinline__ float bflo(uint32_t v) {
    union { uint32_t u; float f; } x; x.u = v << 16; return x.f;
}
__device__ __forceinline__ float bfhi(uint32_t v) {
    union { uint32_t u; float f; } x; x.u = v & 0xffff0000u; return x.f;
}
__device__ __forceinline__ uint32_t pk2(float lo, float hi) {
    return (uint32_t)(uint16_t)f2bf(lo) | ((uint32_t)(uint16_t)f2bf(hi) << 16);
}

// ---------------------------------------------------------------------------
// int64-vs-int32 layout detection (wave-parallel)
// ---------------------------------------------------------------------------
__global__ void detect64_kernel(const int* __restrict__ ei, int* __restrict__ flag) {
    int lane = threadIdx.x & 63;
    int v = ei[2 * lane + 1];
    unsigned long long b = __ballot(v == 0);
    if (threadIdx.x == 0) *flag = (b == ~0ULL) ? 1 : 0;
}

__device__ __forceinline__ int fetch_idx(const int* __restrict__ p, long j, int f64) {
    return p[f64 ? (j << 1) : j];
}

// ---------------------------------------------------------------------------
// CSR pass A: writer-partitioned bin scatter, 64 writer groups.
// ---------------------------------------------------------------------------
__global__ void __launch_bounds__(256) bin_scatter_kernel(
        const int* __restrict__ ei, const int* __restrict__ flag,
        int* __restrict__ cnt, uint32_t* __restrict__ binned,
        long E, int NBIN, int NBINP) {
    const int group = blockIdx.x & (NGROUP - 1);
    const int f = *flag;
    const long stride = (long)gridDim.x * blockDim.x;
    for (long e = (long)blockIdx.x * blockDim.x + threadIdx.x; e < E; e += stride) {
        int s = fetch_idx(ei, e, f);
        int d = fetch_idx(ei, E + e, f);
        int b = d >> 8;
        int pos = atomicAdd(&cnt[group * NBINP + b], 1);
        if (pos < CAP)
            binned[((size_t)group * NBIN + b) * CAP + pos] =
                (uint32_t)s | ((uint32_t)(d & (PSIZE - 1)) << 20);
    }
}

// bin totals = sum over the 64 group counters
__global__ void bintot_kernel(const int* __restrict__ cnt, int* __restrict__ bin_tot,
                              int NBIN, int NBINP) {
    int b = blockIdx.x * blockDim.x + threadIdx.x;
    if (b < NBIN) {
        int s = 0;
#pragma unroll
        for (int g = 0; g < NGROUP; ++g) s += cnt[g * NBINP + b];
        bin_tot[b] = s;
    }
}

// generic single-block exclusive scan (bin offsets)
__global__ void __launch_bounds__(1024) scan_kernel(const int* __restrict__ deg,
                                                    int* __restrict__ ofs, int n) {
    __shared__ int wsum[16];
    __shared__ int carry_s;
    __shared__ int chunk_tot;
    const int tid  = threadIdx.x;
    const int lane = tid & 63;
    const int wid  = tid >> 6;
    if (tid == 0) carry_s = 0;
    __syncthreads();
    const int CHUNK = 4096;
    for (int base = 0; base < n; base += CHUNK) {
        int idx = base + tid * 4;
        int v[4];
#pragma unroll
        for (int j = 0; j < 4; ++j) v[j] = (idx + j < n) ? deg[idx + j] : 0;
        int s1 = v[0] + v[1] + v[2] + v[3];
        int inc = s1;
#pragma unroll
        for (int d = 1; d < 64; d <<= 1) {
            int t = __shfl_up(inc, d, 64);
            if (lane >= d) inc += t;
        }
        if (lane == 63) wsum[wid] = inc;
        __syncthreads();
        if (wid == 0) {
            int ws = (lane < 16) ? wsum[lane] : 0;
            int winc = ws;
#pragma unroll
            for (int d = 1; d < 16; d <<= 1) {
                int t = __shfl_up(winc, d, 64);
                if (lane >= d) winc += t;
            }
            if (lane == 15) chunk_tot = winc;
            if (lane < 16) wsum[lane] = winc - ws;
        }
        __syncthreads();
        int excl = carry_s + wsum[wid] + (inc - s1);
        int run = excl;
#pragma unroll
        for (int j = 0; j < 4; ++j) {
            if (idx + j < n) ofs[idx + j] = run;
            run += v[j];
        }
        __syncthreads();
        if (tid == 0) carry_s += chunk_tot;
        __syncthreads();
    }
    if (tid == 0) ofs[n] = carry_s;
}

// ---------------------------------------------------------------------------
// CSR pass B: one block per bin; LDS histogram -> scan -> scatter; ofs + dinv.
// ---------------------------------------------------------------------------
__global__ void __launch_bounds__(512) bin_build_kernel(
        const uint32_t* __restrict__ binned, const int* __restrict__ cnt,
        const int* __restrict__ bofs, int* __restrict__ ofs,
        float* __restrict__ dinv, int* __restrict__ col,
        int n, int NBIN, int NBINP, long E) {
    __shared__ int lcnt[PSIZE];
    __shared__ int lofs[PSIZE];
    __shared__ int lrank[PSIZE];
    __shared__ int wtot[4];
    const int b    = blockIdx.x;
    const int v0   = b * PSIZE;
    const int nn   = min(PSIZE, n - v0);
    const int tid  = threadIdx.x;
    const int wv   = tid >> 6;      // 0..7
    const int lane = tid & 63;
    if (tid < PSIZE) { lcnt[tid] = 0; lrank[tid] = 0; }
    __syncthreads();
#pragma unroll
    for (int sg = wv; sg < NGROUP; sg += 8) {
        const int c = min(cnt[sg * NBINP + b], CAP);
        const uint32_t* __restrict__ src = binned + ((size_t)sg * NBIN + b) * CAP;
        for (int i = lane; i < c; i += 64)
            atomicAdd(&lcnt[src[i] >> 20], 1);
    }
    __syncthreads();
    if (tid < PSIZE) {               // 4-wave two-level scan of lcnt
        int v = lcnt[tid];
        int inc = v;
#pragma unroll
        for (int d = 1; d < 64; d <<= 1) {
            int t = __shfl_up(inc, d, 64);
            if (lane >= d) inc += t;
        }
        if (lane == 63) wtot[wv] = inc;
        lofs[tid] = inc - v;
    }
    __syncthreads();
    if (tid < PSIZE) {
        int add = 0;
#pragma unroll
        for (int k = 0; k < 4; ++k) if (k < wv) add += wtot[k];
        lofs[tid] += add;
    }
    __syncthreads();
    const int base = bofs[b];
#pragma unroll
    for (int sg = wv; sg < NGROUP; sg += 8) {
        const int c = min(cnt[sg * NBINP + b], CAP);
        const uint32_t* __restrict__ src = binned + ((size_t)sg * NBIN + b) * CAP;
        for (int i = lane; i < c; i += 64) {
            uint32_t v = src[i];
            int dl = (int)(v >> 20);
            int rk = atomicAdd(&lrank[dl], 1);
            col[base + lofs[dl] + rk] = (int)(v & 0xFFFFFu);
        }
    }
    if (tid < nn) {
        ofs[v0 + tid]  = base + lofs[tid];
        dinv[v0 + tid] = rsqrtf((float)lcnt[tid] + 1.0f);
    }
    if (tid == 0 && v0 + nn == n) ofs[n] = (int)E;
}

// ---------------------------------------------------------------------------
// Weight prep: Wt[w] = transpose(W_w) split into bf16 hi + lo planes.
// ---------------------------------------------------------------------------
__global__ void __launch_bounds__(128) wprep_kernel(
        const float* __restrict__ W0, const float* __restrict__ W1,
        const float* __restrict__ W2, short* __restrict__ Wt) {
    const float* W = (blockIdx.x == 0) ? W0 : (blockIdx.x == 1) ? W1 : W2;
    short* hi = Wt + (size_t)blockIdx.x * 2 * HID * HID;
    short* lo = hi + HID * HID;
    __shared__ float Ws[64][129];
    const int t = threadIdx.x;
    for (int half = 0; half < 2; ++half) {
        const int kbase = half * 64;
#pragma unroll
        for (int it = 0; it < 16; ++it) {
            int idx = (t + it * 128) * 4;
            int k = idx >> 7, c = idx & 127;
            float4 v = *(const float4*)(W + (size_t)(kbase + k) * HID + c);
            Ws[k][c] = v.x; Ws[k][c + 1] = v.y; Ws[k][c + 2] = v.z; Ws[k][c + 3] = v.w;
        }
        __syncthreads();
        for (int it = 0; it < 64; ++it) {
            int k2 = t & 63;
            int c  = (t >> 6) + it * 2;
            float w = Ws[k2][c];
            short h = f2bf(w);
            hi[(size_t)c * HID + kbase + k2] = h;
            lo[(size_t)c * HID + kbase + k2] = f2bf(w - bf2f(h));
        }
        __syncthreads();
    }
}

// ---------------------------------------------------------------------------
// hs = bf16( (A @ W) * dinv[:,None] ) — MFMA bf16, LDS-free, split-W hi+lo.
// ---------------------------------------------------------------------------
template<bool AFP32>
__global__ void __launch_bounds__(256) gemm_hs_kernel(
        const void* __restrict__ Ap, const short* __restrict__ Wt,
        const float* __restrict__ dinv, short* __restrict__ hs, int n) {
    const short* __restrict__ Bh = Wt;
    const short* __restrict__ Bl = Wt + HID * HID;
    const int tid = threadIdx.x;
    const int w  = tid >> 6;
    const int l  = tid & 63;
    const int lr = l & 15;
    const int kq = l >> 4;
    const int r0 = blockIdx.x * 128;

    f32x4 acc[8][2] = {};
    const int col0 = w * 32 + lr;
    const int col1 = w * 32 + 16 + lr;

    const float* Af = (const float*)Ap;
    const short* Ab = (const short*)Ap;

#pragma unroll
    for (int ks = 0; ks < 4; ++ks) {
        const int k0 = ks * 32 + kq * 8;
        bf16x8 a[8];
#pragma unroll
        for (int rf = 0; rf < 8; ++rf) {
            int row = r0 + rf * 16 + lr;
            if (row >= n) row = n - 1;
            if (AFP32) {
                const float* ap = Af + (size_t)row * HID + k0;
                float4 f0 = *(const float4*)ap;
                float4 f1 = *(const float4*)(ap + 4);
                bf16x8 tv;
                tv[0] = f2bf(f0.x); tv[1] = f2bf(f0.y); tv[2] = f2bf(f0.z); tv[3] = f2bf(f0.w);
                tv[4] = f2bf(f1.x); tv[5] = f2bf(f1.y); tv[6] = f2bf(f1.z); tv[7] = f2bf(f1.w);
                a[rf] = tv;
            } else {
                a[rf] = *(const bf16x8*)(Ab + (size_t)row * HID + k0);
            }
        }
        bf16x8 bh0 = *(const bf16x8*)(Bh + (size_t)col0 * HID + k0);
        bf16x8 bh1 = *(const bf16x8*)(Bh + (size_t)col1 * HID + k0);
        bf16x8 bl0 = *(const bf16x8*)(Bl + (size_t)col0 * HID + k0);
        bf16x8 bl1 = *(const bf16x8*)(Bl + (size_t)col1 * HID + k0);
#pragma unroll
        for (int rf = 0; rf < 8; ++rf) {
            acc[rf][0] = __builtin_amdgcn_mfma_f32_16x16x32_bf16(a[rf], bh0, acc[rf][0], 0, 0, 0);
            acc[rf][1] = __builtin_amdgcn_mfma_f32_16x16x32_bf16(a[rf], bh1, acc[rf][1], 0, 0, 0);
            acc[rf][0] = __builtin_amdgcn_mfma_f32_16x16x32_bf16(a[rf], bl0, acc[rf][0], 0, 0, 0);
            acc[rf][1] = __builtin_amdgcn_mfma_f32_16x16x32_bf16(a[rf], bl1, acc[rf][1], 0, 0, 0);
        }
    }
#pragma unroll
    for (int rf = 0; rf < 8; ++rf) {
#pragma unroll
        for (int rg = 0; rg < 4; ++rg) {
            int row = r0 + rf * 16 + kq * 4 + rg;
            if (row < n) {
                float dn = dinv[row];
                hs[(size_t)row * HID + col0] = f2bf(acc[rf][0][rg] * dn);
                hs[(size_t)row * HID + col1] = f2bf(acc[rf][1][rg] * dn);
            }
        }
    }
}

// ---------------------------------------------------------------------------
// out[d] = maybe_relu( dinv[d] * (hs[d] + sum_{e->d} hs[src]) + bias )  (bf16)
// One wave per node; 16 lanes per row (dwordx4), 4 rows per gather instr,
// up to 16 rows in flight. Cross-group combine: 2 shfl_xor steps.
// ---------------------------------------------------------------------------
__device__ __forceinline__ void acc_add(float* acc, uint4 v) {
    acc[0] += bflo(v.x); acc[1] += bfhi(v.x);
    acc[2] += bflo(v.y); acc[3] += bfhi(v.y);
    acc[4] += bflo(v.z); acc[5] += bfhi(v.z);
    acc[6] += bflo(v.w); acc[7] += bfhi(v.w);
}

__global__ void __launch_bounds__(256) agg_kernel(
        const short* __restrict__ hs, const float* __restrict__ dinv,
        const int* __restrict__ ofs, const int* __restrict__ col,
        const float* __restrict__ bias, short* __restrict__ out,
        int n, int do_relu) {
    int node = blockIdx.x * 4 + (threadIdx.x >> 6);
    if (node >= n) return;
    const int lane = threadIdx.x & 63;
    const int g    = lane >> 4;      // row-group 0..3
    const int sub  = lane & 15;      // 16B chunk within row
    const uint4* __restrict__ rows = (const uint4*)hs;   // one row = 16 uint4

    float acc[8] = {0.f, 0.f, 0.f, 0.f, 0.f, 0.f, 0.f, 0.f};
    if (g == 0) {                    // self term (hs already *dinv)
        uint4 sv = rows[(size_t)node * 16 + sub];
        acc_add(acc, sv);
    }
    const int e0 = ofs[node], e1 = ofs[node + 1];
    int e = e0;
    for (; e + 16 <= e1; e += 16) {  // 16 rows in flight
        int c0 = col[e + g];
        int c1 = col[e + 4 + g];
        int c2 = col[e + 8 + g];
        int c3 = col[e + 12 + g];
        uint4 v0 = rows[(size_t)c0 * 16 + sub];
        uint4 v1 = rows[(size_t)c1 * 16 + sub];
        uint4 v2 = rows[(size_t)c2 * 16 + sub];
        uint4 v3 = rows[(size_t)c3 * 16 + sub];
        acc_add(acc, v0); acc_add(acc, v1); acc_add(acc, v2); acc_add(acc, v3);
    }
    for (; e + 4 <= e1; e += 4) {
        int c0 = col[e + g];
        uint4 v0 = rows[(size_t)c0 * 16 + sub];
        acc_add(acc, v0);
    }
    if (e + g < e1) {                // tail (<4 edges): one row per live group
        int c0 = col[e + g];
        uint4 v0 = rows[(size_t)c0 * 16 + sub];
        acc_add(acc, v0);
    }
#pragma unroll
    for (int i = 0; i < 8; ++i) {    // combine the 4 row-groups
        acc[i] += __shfl_xor(acc[i], 16, 64);
        acc[i] += __shfl_xor(acc[i], 32, 64);
    }
    if (g == 0) {
        const float dn = dinv[node];
        float4 b0 = *(const float4*)(bias + 8 * sub);
        float4 b1 = *(const float4*)(bias + 8 * sub + 4);
        float o0 = fmaf(acc[0], dn, b0.x);
        float o1 = fmaf(acc[1], dn, b0.y);
        float o2 = fmaf(acc[2], dn, b0.z);
        float o3 = fmaf(acc[3], dn, b0.w);
        float o4 = fmaf(acc[4], dn, b1.x);
        float o5 = fmaf(acc[5], dn, b1.y);
        float o6 = fmaf(acc[6], dn, b1.z);
        float o7 = fmaf(acc[7], dn, b1.w);
        if (do_relu) {
            o0 = fmaxf(o0, 0.f); o1 = fmaxf(o1, 0.f);
            o2 = fmaxf(o2, 0.f); o3 = fmaxf(o3, 0.f);
            o4 = fmaxf(o4, 0.f); o5 = fmaxf(o5, 0.f);
            o6 = fmaxf(o6, 0.f); o7 = fmaxf(o7, 0.f);
        }
        uint4 pk;
        pk.x = pk2(o0, o1); pk.y = pk2(o2, o3);
        pk.z = pk2(o4, o5); pk.w = pk2(o6, o7);
        ((uint4*)out)[(size_t)node * 16 + sub] = pk;
    }
}

// ---------------------------------------------------------------------------
// pooling + MLP head
// ---------------------------------------------------------------------------
__global__ void boundary_kernel(const int* __restrict__ batch, const int* __restrict__ flag,
                                int* __restrict__ gstart, int n) {
    int i = blockIdx.x * blockDim.x + threadIdx.x;
    if (i >= n) return;
    int f = *flag;
    int b  = fetch_idx(batch, i, f);
    int bp = (i == 0) ? -1 : fetch_idx(batch, i - 1, f);
    for (int g = bp + 1; g <= b; ++g) gstart[g] = i;
    if (i == n - 1) {
        for (int g = b + 1; g <= NGRAPH; ++g) gstart[g] = n;
    }
}

__global__ void __launch_bounds__(128) pool_kernel(const short* __restrict__ h,
                                                   const int* __restrict__ gstart,
                                                   float* __restrict__ pooled) {
    int g = blockIdx.x, c = threadIdx.x;
    int s = gstart[g], e = gstart[g + 1];
    float acc = 0.f;
    int i = s;
    for (; i + 4 <= e; i += 4) {
        acc += bf2f(h[(size_t)i * HID + c]) + bf2f(h[(size_t)(i + 1) * HID + c])
             + bf2f(h[(size_t)(i + 2) * HID + c]) + bf2f(h[(size_t)(i + 3) * HID + c]);
    }
    for (; i < e; ++i) acc += bf2f(h[(size_t)i * HID + c]);
    float cnt = (float)(e - s);
    pooled[g * HID + c] = acc / fmaxf(cnt, 1.f);
}

__global__ void __launch_bounds__(128) mlp_kernel(
        const float* __restrict__ pooled,
        const float* __restrict__ W1, const float* __restrict__ b1,
        const float* __restrict__ W2, const float* __restrict__ b2,
        float* __restrict__ out) {
    __shared__ float p[HID];
    __shared__ float hid[HID];
    int g = blockIdx.x, c = threadIdx.x;
    p[c] = pooled[g * HID + c];
    __syncthreads();
    float a = b1[c];
#pragma unroll 8
    for (int k = 0; k < HID; ++k) a = fmaf(p[k], W1[k * HID + c], a);
    hid[c] = fmaxf(a, 0.f);
    __syncthreads();
    if (c < OUTC) {
        float o = b2[c];
#pragma unroll 8
        for (int k = 0; k < HID; ++k) o = fmaf(hid[k], W2[k * OUTC + c], o);
        out[g * OUTC + c] = o;
    }
}

// ---------------------------------------------------------------------------
extern "C" void kernel_launch(void* const* d_in, const int* in_sizes, int n_in,
                              void* d_out, int out_size, void* d_ws, size_t ws_size,
                              hipStream_t stream) {
    const float* x   = (const float*)d_in[0];
    const int*   ei  = (const int*)d_in[1];
    const int*   bat = (const int*)d_in[2];
    const float* Wc0 = (const float*)d_in[3];
    const float* bc0 = (const float*)d_in[4];
    const float* Wc1 = (const float*)d_in[5];
    const float* bc1 = (const float*)d_in[6];
    const float* Wc2 = (const float*)d_in[7];
    const float* bc2 = (const float*)d_in[8];
    const float* W1  = (const float*)d_in[9];
    const float* b1  = (const float*)d_in[10];
    const float* W2  = (const float*)d_in[11];
    const float* b2  = (const float*)d_in[12];
    float* out = (float*)d_out;

    const int  n = in_sizes[0] / HID;             // 100000 (< 2^20)
    const long E = in_sizes[1] / 2;
    const int  NBIN  = (n + PSIZE - 1) / PSIZE;   // 391
    const int  NBINP = (NBIN + 15) & ~15;         // 400: per-group counters line-aligned

    char* w = (char*)d_ws;
    size_t off = 0;
    auto carve = [&](size_t bytes) {
        void* p = w + off;
        off += (bytes + 255) & ~(size_t)255;
        return p;
    };
    int*   flag    = (int*)carve(4);
    int*   cnt     = (int*)carve((size_t)NGROUP * NBINP * 4);
    int*   bin_tot = (int*)carve((size_t)NBIN * 4);
    int*   bofs    = (int*)carve((size_t)(NBIN + 1) * 4);
    int*   ofs     = (int*)carve((size_t)(n + 1) * 4);
    float* dinv    = (float*)carve((size_t)n * 4);
    int*   gstart  = (int*)carve((NGRAPH + 1) * 4);
    int*   col     = (int*)carve((size_t)E * 4);
    short* Wt      = (short*)carve((size_t)3 * 2 * HID * HID * 2);
    short* hs      = (short*)carve((size_t)n * HID * 2);
    short* h       = (short*)carve((size_t)n * HID * 2);
    float* pooled  = (float*)carve((size_t)NGRAPH * HID * 4);
    uint32_t* binned = (uint32_t*)h;  // 64*391*160*4 = 16.0 MB <= 25.6 MB (h), dead before h written

    hipMemsetAsync(cnt, 0, (size_t)NGROUP * NBINP * 4, stream);

    detect64_kernel<<<1, 64, 0, stream>>>(ei, flag);

    bin_scatter_kernel<<<2048, 256, 0, stream>>>(ei, flag, cnt, binned, E, NBIN, NBINP);
    bintot_kernel<<<(NBIN + 255) / 256, 256, 0, stream>>>(cnt, bin_tot, NBIN, NBINP);
    scan_kernel<<<1, 1024, 0, stream>>>(bin_tot, bofs, NBIN);
    bin_build_kernel<<<NBIN, 512, 0, stream>>>(binned, cnt, bofs, ofs, dinv, col,
                                               n, NBIN, NBINP, E);
    wprep_kernel<<<3, 128, 0, stream>>>(Wc0, Wc1, Wc2, Wt);

    const int gb = (n + 127) / 128;
    const int ab = (n + 3) / 4;
    const size_t WSTRIDE = (size_t)2 * HID * HID;
    // layer 0
    gemm_hs_kernel<true><<<gb, 256, 0, stream>>>(x, Wt, dinv, hs, n);
    agg_kernel<<<ab, 256, 0, stream>>>(hs, dinv, ofs, col, bc0, h, n, 1);
    // layer 1
    gemm_hs_kernel<false><<<gb, 256, 0, stream>>>(h, Wt + WSTRIDE, dinv, hs, n);
    agg_kernel<<<ab, 256, 0, stream>>>(hs, dinv, ofs, col, bc1, h, n, 1);
    // layer 2 (no relu)
    gemm_hs_kernel<false><<<gb, 256, 0, stream>>>(h, Wt + 2 * WSTRIDE, dinv, hs, n);
    agg_kernel<<<ab, 256, 0, stream>>>(hs, dinv, ofs, col, bc2, h, n, 0);

    boundary_kernel<<<(n + 255) / 256, 256, 0, stream>>>(bat, flag, gstart, n);
    pool_kernel<<<NGRAPH, 128, 0, stream>>>(h, gstart, pooled);
    mlp_kernel<<<NGRAPH, 128, 0, stream>>>(pooled, W1, b1, W2, b2, out);
}